// Round 6
// baseline (4650.925 us; speedup 1.0000x reference)
//
#include <hip/hip_runtime.h>
#include <cstdint>
#include <cstddef>

#define T_STEPS 256
#define B_DIM   64
#define D_DIM   768
#define R_DIM   2048
#define NBLK    256
#define NTHR    512

// LDS layout (dynamic): Whi frag [64 chunks][64 lanes][8 bf16] = 64 KB
//                       Wlo frag same                          = 64 KB
//                       partial  [8 waves][64 lanes][4 f32]    =  8 KB
#define S_WHI_OFF  0
#define S_WLO_OFF  65536
#define S_PART_OFF 131072
#define S_TOTAL    139264

using short8 = __attribute__((ext_vector_type(8))) short;
using f32x4  = __attribute__((ext_vector_type(4))) float;

struct U128 { uint64_t a, b; };
static __device__ __forceinline__ short8 cat2(uint64_t a, uint64_t b) {
  return __builtin_bit_cast(short8, U128{a, b});
}

__device__ __forceinline__ uint16_t f2bf(float f) {
  uint32_t u = __builtin_bit_cast(uint32_t, f);
  u += 0x7fffu + ((u >> 16) & 1u);   // round-to-nearest-even
  return (uint16_t)(u >> 16);
}
__device__ __forceinline__ float bf2f(uint16_t h) {
  uint32_t u = ((uint32_t)h) << 16;
  return __builtin_bit_cast(float, u);
}

// agent-scope (sc1) accesses: bypass L1/L2, coherent at L3 — no fences needed
__device__ __forceinline__ void st32_agent(uint32_t* p, uint32_t v) {
  __hip_atomic_store(p, v, __ATOMIC_RELAXED, __HIP_MEMORY_SCOPE_AGENT);
}
__device__ __forceinline__ uint32_t ld32_agent(const uint32_t* p) {
  return __hip_atomic_load(p, __ATOMIC_RELAXED, __HIP_MEMORY_SCOPE_AGENT);
}
__device__ __forceinline__ uint64_t ld64_agent(const uint64_t* p) {
  return __hip_atomic_load(p, __ATOMIC_RELAXED, __HIP_MEMORY_SCOPE_AGENT);
}

// ---- prep kernels ----
__global__ void k_split_w(const float* __restrict__ w, uint16_t* __restrict__ hi,
                          uint16_t* __restrict__ lo, int n) {
  for (int i = blockIdx.x * blockDim.x + threadIdx.x; i < n;
       i += gridDim.x * blockDim.x) {
    float f = w[i];
    uint16_t h = f2bf(f);
    hi[i] = h;
    lo[i] = f2bf(f - bf2f(h));
  }
}

__global__ void k_tobf(const float* __restrict__ src, uint16_t* __restrict__ dst,
                       int n) {
  for (int i = blockIdx.x * blockDim.x + threadIdx.x; i < n;
       i += gridDim.x * blockDim.x)
    dst[i] = f2bf(src[i]);
}

__global__ void k_init_x(const float* __restrict__ init,
                         uint16_t* __restrict__ hi, uint16_t* __restrict__ lo,
                         uint32_t* __restrict__ flags) {
  int i = blockIdx.x * blockDim.x + threadIdx.x;
  if (i < NBLK * 16) flags[i] = 0u;          // 64B-spaced barrier flags
  if (i < B_DIM * R_DIM) {
    float f = init[i & (R_DIM - 1)];
    uint16_t h = f2bf(f);
    hi[i] = h;
    lo[i] = f2bf(f - bf2f(h));
  }
}

// ---- persistent ESN kernel ----
// 256 blocks: bid>>7 = batch half (32 rows), bid&127 = n-tile (16 cols).
// 8 waves: w>>2 = m-subtile (16 rows), w&3 = K-split group (512 k each).
// W slice in LDS (fragment layout, conflict-free).
// Cross-step x exchanged entirely via sc1 (L2-bypass) accesses — NO fences:
// writes land at L3 before flag set (vmcnt0), reads are served from L3.
// Read-only data (Iw, u) stays L2-cached forever (never invalidated).
__global__ __launch_bounds__(NTHR, 2)
void k_persist(const uint16_t* __restrict__ Whi, const uint16_t* __restrict__ Wlo,
               const uint16_t* __restrict__ Iwb, const uint16_t* __restrict__ ubf,
               const float* __restrict__ init,
               uint16_t* __restrict__ xh, uint16_t* __restrict__ xl,
               const float* __restrict__ bias, const int* __restrict__ lengths,
               float* __restrict__ out, uint32_t* __restrict__ flags)
{
  extern __shared__ char smem[];
  uint16_t* s_whi  = (uint16_t*)(smem + S_WHI_OFF);
  uint16_t* s_wlo  = (uint16_t*)(smem + S_WLO_OFF);
  float*    s_part = (float*)(smem + S_PART_OFF);

  const int bid  = blockIdx.x;
  const int h    = bid >> 7;           // batch half
  const int n0   = (bid & 127) * 16;   // output column base
  const int tid  = threadIdx.x;
  const int w    = tid >> 6;
  const int lane = tid & 63;
  const int kg   = w & 3;              // K-split group
  const int mt   = h * 32 + (w >> 2) * 16;  // batch-row tile base
  const int fr   = lane & 15;
  const int koffe = (lane >> 4) << 3;  // 0,8,16,24 element offset

  // preload W slice (16 cols x 2048 k, hi+lo) into LDS, fragment layout
  for (int s = tid; s < 4096; s += NTHR) {
    int ch = s >> 6, l = s & 63;
    size_t g = (size_t)(n0 + (l & 15)) * R_DIM + (size_t)ch * 32 + ((l >> 4) << 3);
    *(short8*)(s_whi + (size_t)s * 8) = *(const short8*)(Whi + g);
    *(short8*)(s_wlo + (size_t)s * 8) = *(const short8*)(Wlo + g);
  }
  __syncthreads();

  // epilogue mapping: 256 threads x 2 adjacent cols
  float biasA = 0.f, biasB = 0.f;
  float xoA = 0.f, xoB = 0.f;          // running state held in registers
  int   len_ep = 0, r_ep = 0, c0_ep = 0, b_ep = 0;
  if (tid < 256) {
    r_ep  = tid >> 3;            // 0..31
    c0_ep = (tid & 7) << 1;      // 0,2,..,14
    b_ep  = h * 32 + r_ep;
    biasA = bias[n0 + c0_ep];
    biasB = bias[n0 + c0_ep + 1];
    xoA   = init[n0 + c0_ep];
    xoB   = init[n0 + c0_ep + 1];
    len_ep = lengths[b_ep];
  }
  const int mw_ep = (r_ep >> 4) << 2;
  const int lq_ep = (r_ep & 15) >> 2;
  const int j_ep  = r_ep & 3;

  // prefetch u fragments for step 0
  short8 au[6];
  {
    const uint16_t* u_row = ubf + ((size_t)0 * B_DIM + mt + fr) * D_DIM + kg * 192 + koffe;
#pragma unroll
    for (int i = 0; i < 6; ++i) au[i] = *(const short8*)(u_row + i * 32);
  }

  for (int t = 0; t < T_STEPS; ++t) {
    const int cur = t & 1, nxt = cur ^ 1;
    const uint16_t* xhc = xh + (size_t)cur * B_DIM * R_DIM;
    const uint16_t* xlc = xl + (size_t)cur * B_DIM * R_DIM;

    // ---- recurrent MFMA phase (split bf16, K-split); x via sc1 u64 loads ----
    f32x4 acc = {0.f, 0.f, 0.f, 0.f};
    const uint64_t* xh_q = (const uint64_t*)(xhc + (size_t)(mt + fr) * R_DIM + koffe);
    const uint64_t* xl_q = (const uint64_t*)(xlc + (size_t)(mt + fr) * R_DIM + koffe);
#pragma unroll 4
    for (int i = 0; i < 16; ++i) {
      const int ch = kg * 16 + i;
      uint64_t h0 = ld64_agent(xh_q + (size_t)ch * 8);
      uint64_t h1 = ld64_agent(xh_q + (size_t)ch * 8 + 1);
      uint64_t l0 = ld64_agent(xl_q + (size_t)ch * 8);
      uint64_t l1 = ld64_agent(xl_q + (size_t)ch * 8 + 1);
      short8 ah = cat2(h0, h1);
      short8 al = cat2(l0, l1);
      short8 bh = *(const short8*)(s_whi + (size_t)(ch * 64 + lane) * 8);
      short8 bl = *(const short8*)(s_wlo + (size_t)(ch * 64 + lane) * 8);
      acc = __builtin_amdgcn_mfma_f32_16x16x32_bf16(ah, bh, acc, 0, 0, 0);
      acc = __builtin_amdgcn_mfma_f32_16x16x32_bf16(ah, bl, acc, 0, 0, 0);
      acc = __builtin_amdgcn_mfma_f32_16x16x32_bf16(al, bh, acc, 0, 0, 0);
    }
    // ---- input projection (single bf16, prefetched u regs; Iw from L2) ----
    const uint16_t* iw_row = Iwb + (size_t)(n0 + fr) * D_DIM + kg * 192 + koffe;
#pragma unroll
    for (int i = 0; i < 6; ++i) {
      short8 bi = *(const short8*)(iw_row + i * 32);
      acc = __builtin_amdgcn_mfma_f32_16x16x32_bf16(au[i], bi, acc, 0, 0, 0);
    }

    // ---- K-split reduce through LDS ----
    *(f32x4*)(s_part + ((size_t)w * 64 + lane) * 4) = acc;
    __syncthreads();

    // ---- epilogue: 2 cols per thread; x-state in regs; out = plain stores ----
    if (tid < 256) {
      float pre0 = biasA, pre1 = biasB;
#pragma unroll
      for (int g2 = 0; g2 < 4; ++g2) {
        const int base = ((mw_ep + g2) * 64 + lq_ep * 16) * 4 + j_ep;
        pre0 += s_part[base + (c0_ep) * 4];
        pre1 += s_part[base + (c0_ep + 1) * 4];
      }
      float xn0 = 0.5f * xoA + 0.5f * tanhf(pre0);
      float xn1 = 0.5f * xoB + 0.5f * tanhf(pre1);
      if (t >= len_ep) { xn0 = 0.f; xn1 = 0.f; }
      xoA = xn0; xoB = xn1;
      // out: plain cached store (no device reader; kernel-end flush publishes)
      *(float2*)(out + ((size_t)b_ep * T_STEPS + t) * R_DIM + n0 + c0_ep) =
          make_float2(xn0, xn1);
      uint16_t* xhn = xh + (size_t)nxt * B_DIM * R_DIM;
      uint16_t* xln = xl + (size_t)nxt * B_DIM * R_DIM;
      const uint16_t h0 = f2bf(xn0), h1 = f2bf(xn1);
      const uint16_t l0 = f2bf(xn0 - bf2f(h0)), l1 = f2bf(xn1 - bf2f(h1));
      st32_agent((uint32_t*)(xhn + (size_t)b_ep * R_DIM + n0 + c0_ep),
                 (uint32_t)h0 | ((uint32_t)h1 << 16));
      st32_agent((uint32_t*)(xln + (size_t)b_ep * R_DIM + n0 + c0_ep),
                 (uint32_t)l0 | ((uint32_t)l1 << 16));
    }

    if (t == T_STEPS - 1) break;       // no barrier needed after last step

    // ---- flag-array grid barrier (RMW-free, fence-free) ----
    asm volatile("s_waitcnt vmcnt(0)" ::: "memory");  // x stores acked at L3
    __syncthreads();                                  // whole block done
    // prefetch next step's u (read-only; latency hides under the poll)
    {
      const uint16_t* u_row = ubf + ((size_t)(t + 1) * B_DIM + mt + fr) * D_DIM + kg * 192 + koffe;
#pragma unroll
      for (int i = 0; i < 6; ++i) au[i] = *(const short8*)(u_row + i * 32);
    }
    if (w == 0) {
      st32_agent(flags + (size_t)bid * 16, (uint32_t)(t + 1));
      const uint32_t tgt = (uint32_t)(t + 1);
      for (;;) {
        bool ok = true;
#pragma unroll
        for (int r = 0; r < 4; ++r) {
          uint32_t v = ld32_agent(flags + (size_t)(r * 64 + lane) * 16);
          ok &= (v >= tgt);
        }
        if (__all(ok)) break;
        __builtin_amdgcn_s_sleep(1);
      }
    }
    __syncthreads();
    asm volatile("" ::: "memory");
  }
}

extern "C" void kernel_launch(void* const* d_in, const int* in_sizes, int n_in,
                              void* d_out, int out_size, void* d_ws, size_t ws_size,
                              hipStream_t stream) {
  const float* embedded    = (const float*)d_in[0];
  const int*   lengths     = (const int*)d_in[1];
  const float* input_w     = (const float*)d_in[2];
  const float* reservoir_w = (const float*)d_in[3];
  const float* bias        = (const float*)d_in[4];
  const float* init        = (const float*)d_in[5];
  float* out = (float*)d_out;

  // workspace carve (~45 MB)
  char* p = (char*)d_ws;
  uint16_t* Whi = (uint16_t*)p; p += (size_t)R_DIM * R_DIM * 2;
  uint16_t* Wlo = (uint16_t*)p; p += (size_t)R_DIM * R_DIM * 2;
  uint16_t* Iwb = (uint16_t*)p; p += (size_t)R_DIM * D_DIM * 2;
  uint16_t* ubf = (uint16_t*)p; p += (size_t)T_STEPS * B_DIM * D_DIM * 2;
  uint16_t* xh  = (uint16_t*)p; p += (size_t)2 * B_DIM * R_DIM * 2;
  uint16_t* xl  = (uint16_t*)p; p += (size_t)2 * B_DIM * R_DIM * 2;
  uint32_t* flags = (uint32_t*)p; p += (size_t)NBLK * 16 * 4;

  k_split_w<<<1024, 256, 0, stream>>>(reservoir_w, Whi, Wlo, R_DIM * R_DIM);
  k_tobf<<<512, 256, 0, stream>>>(input_w, Iwb, R_DIM * D_DIM);
  k_tobf<<<2048, 256, 0, stream>>>(embedded, ubf, T_STEPS * B_DIM * D_DIM);
  k_init_x<<<(B_DIM * R_DIM) / 256, 256, 0, stream>>>(init, xh, xl, flags);

  (void)hipFuncSetAttribute((const void*)k_persist,
                            hipFuncAttributeMaxDynamicSharedMemorySize, S_TOTAL);

  void* args[] = {(void*)&Whi, (void*)&Wlo, (void*)&Iwb, (void*)&ubf,
                  (void*)&init, (void*)&xh, (void*)&xl, (void*)&bias,
                  (void*)&lengths, (void*)&out, (void*)&flags};
  (void)hipLaunchCooperativeKernel((const void*)k_persist, dim3(NBLK), dim3(NTHR),
                                   args, S_TOTAL, stream);
}

// Round 7
// 3175.466 us; speedup vs baseline: 1.4646x; 1.4646x over previous
//
#include <hip/hip_runtime.h>
#include <cstdint>
#include <cstddef>

#define T_STEPS 256
#define B_DIM   64
#define D_DIM   768
#define R_DIM   2048
#define NBLK    256
#define NTHR    512

// LDS layout (dynamic): Whi frag [64 chunks][64 lanes][8 bf16] = 64 KB
//                       Wlo frag same                          = 64 KB
//                       partial  [8 waves][64 lanes][4 f32]    =  8 KB
#define S_WHI_OFF  0
#define S_WLO_OFF  65536
#define S_PART_OFF 131072
#define S_TOTAL    139264

using short8 = __attribute__((ext_vector_type(8))) short;
using f32x4  = __attribute__((ext_vector_type(4))) float;

__device__ __forceinline__ uint16_t f2bf(float f) {
  uint32_t u = __builtin_bit_cast(uint32_t, f);
  u += 0x7fffu + ((u >> 16) & 1u);   // round-to-nearest-even
  return (uint16_t)(u >> 16);
}
__device__ __forceinline__ float bf2f(uint16_t h) {
  uint32_t u = ((uint32_t)h) << 16;
  return __builtin_bit_cast(float, u);
}

// agent-scope write-through accesses (coherent at L3)
__device__ __forceinline__ void st32_agent(uint32_t* p, uint32_t v) {
  __hip_atomic_store(p, v, __ATOMIC_RELAXED, __HIP_MEMORY_SCOPE_AGENT);
}
__device__ __forceinline__ void st16_agent(uint16_t* p, uint16_t v) {
  __hip_atomic_store(p, v, __ATOMIC_RELAXED, __HIP_MEMORY_SCOPE_AGENT);
}
__device__ __forceinline__ uint32_t ld32_agent(const uint32_t* p) {
  return __hip_atomic_load(p, __ATOMIC_RELAXED, __HIP_MEMORY_SCOPE_AGENT);
}

// ---- prep kernels ----
__global__ void k_split_w(const float* __restrict__ w, uint16_t* __restrict__ hi,
                          uint16_t* __restrict__ lo, int n) {
  for (int i = blockIdx.x * blockDim.x + threadIdx.x; i < n;
       i += gridDim.x * blockDim.x) {
    float f = w[i];
    uint16_t h = f2bf(f);
    hi[i] = h;
    lo[i] = f2bf(f - bf2f(h));
  }
}

__global__ void k_tobf(const float* __restrict__ src, uint16_t* __restrict__ dst,
                       int n) {
  for (int i = blockIdx.x * blockDim.x + threadIdx.x; i < n;
       i += gridDim.x * blockDim.x)
    dst[i] = f2bf(src[i]);
}

__global__ void k_init_x(const float* __restrict__ init,
                         uint16_t* __restrict__ hi, uint16_t* __restrict__ lo,
                         uint32_t* __restrict__ flags) {
  int i = blockIdx.x * blockDim.x + threadIdx.x;
  if (i < NBLK * 16) flags[i] = 0u;          // 64B-spaced barrier flags
  if (i < B_DIM * R_DIM) {
    float f = init[i & (R_DIM - 1)];
    uint16_t h = f2bf(f);
    hi[i] = h;
    lo[i] = f2bf(f - bf2f(h));
  }
}

// ---- persistent ESN kernel ----
// 256 blocks: bid>>7 = batch half (32 rows), bid&127 = n-tile (16 cols).
// 8 waves: w>>2 = m-subtile (16 rows), w&3 = K-split group (512 k each).
// W slice in LDS (fragment layout). Iw fragments live in REGISTERS (loaded
// once; step-invariant). Per step: issue ALL 32 x-loads, run the 6 reg-only
// input-projection MFMAs while they fly, then the recurrent MFMAs.
// x exchange: write-through sc1 stores; plain cached loads after a per-block
// acquire fence hoisted into the barrier wait (R5-proven protocol).
// Grid barrier = per-batch-half flag array (128 blocks each, RMW-free).
__global__ __launch_bounds__(NTHR, 2)
void k_persist(const uint16_t* __restrict__ Whi, const uint16_t* __restrict__ Wlo,
               const uint16_t* __restrict__ Iwb, const uint16_t* __restrict__ ubf,
               const float* __restrict__ init,
               uint16_t* __restrict__ xh, uint16_t* __restrict__ xl,
               const float* __restrict__ bias, const int* __restrict__ lengths,
               float* __restrict__ out, uint32_t* __restrict__ flags)
{
  extern __shared__ char smem[];
  uint16_t* s_whi  = (uint16_t*)(smem + S_WHI_OFF);
  uint16_t* s_wlo  = (uint16_t*)(smem + S_WLO_OFF);
  float*    s_part = (float*)(smem + S_PART_OFF);

  const int bid  = blockIdx.x;
  const int h    = bid >> 7;           // batch half
  const int n0   = (bid & 127) * 16;   // output column base
  const int tid  = threadIdx.x;
  const int w    = tid >> 6;
  const int lane = tid & 63;
  const int kg   = w & 3;              // K-split group
  const int mt   = h * 32 + (w >> 2) * 16;  // batch-row tile base
  const int fr   = lane & 15;
  const int koffe = (lane >> 4) << 3;  // 0,8,16,24 element offset

  // preload W slice (16 cols x 2048 k, hi+lo) into LDS, fragment layout
  for (int s = tid; s < 4096; s += NTHR) {
    int ch = s >> 6, l = s & 63;
    size_t g = (size_t)(n0 + (l & 15)) * R_DIM + (size_t)ch * 32 + ((l >> 4) << 3);
    *(short8*)(s_whi + (size_t)s * 8) = *(const short8*)(Whi + g);
    *(short8*)(s_wlo + (size_t)s * 8) = *(const short8*)(Wlo + g);
  }

  // Iw fragments: step-invariant -> registers, loaded ONCE (L2-invalidate-proof)
  short8 biv[6];
  {
    const uint16_t* iw_row = Iwb + (size_t)(n0 + fr) * D_DIM + kg * 192 + koffe;
#pragma unroll
    for (int i = 0; i < 6; ++i) biv[i] = *(const short8*)(iw_row + i * 32);
  }
  __syncthreads();

  // epilogue mapping: 512 threads x 1 element (row r, col c of the 32x16 tile)
  const int r_ep = tid >> 4;           // 0..31
  const int c_ep = tid & 15;           // 0..15
  const int b_ep = h * 32 + r_ep;
  const float bias_ep = bias[n0 + c_ep];
  float xo = init[n0 + c_ep];          // running state in registers
  const int len_ep = lengths[b_ep];
  const int mw_ep = (r_ep >> 4) << 2;                      // wave group base
  const int l_ep  = ((((r_ep & 15) >> 2)) << 4) | c_ep;    // lane within wave
  const int j_ep  = r_ep & 3;

  // prefetch u fragments for step 0
  short8 au[6];
  {
    const uint16_t* u_row = ubf + ((size_t)0 * B_DIM + mt + fr) * D_DIM + kg * 192 + koffe;
#pragma unroll
    for (int i = 0; i < 6; ++i) au[i] = *(const short8*)(u_row + i * 32);
  }

  for (int t = 0; t < T_STEPS; ++t) {
    const int cur = t & 1, nxt = cur ^ 1;
    const uint16_t* xh_row = xh + (size_t)cur * B_DIM * R_DIM + (size_t)(mt + fr) * R_DIM + koffe;
    const uint16_t* xl_row = xl + (size_t)cur * B_DIM * R_DIM + (size_t)(mt + fr) * R_DIM + koffe;

    // ---- issue ALL x loads up front (32 b128 in flight) ----
    short8 ahv[16], alv[16];
#pragma unroll 16
    for (int i = 0; i < 16; ++i) {
      const int ch = kg * 16 + i;
      ahv[i] = *(const short8*)(xh_row + ch * 32);
      alv[i] = *(const short8*)(xl_row + ch * 32);
    }

    // ---- input projection (register-only MFMAs; hides x-load latency) ----
    f32x4 acc = {0.f, 0.f, 0.f, 0.f};
#pragma unroll
    for (int i = 0; i < 6; ++i)
      acc = __builtin_amdgcn_mfma_f32_16x16x32_bf16(au[i], biv[i], acc, 0, 0, 0);

    // ---- recurrent MFMA phase (split bf16, K-split) ----
#pragma unroll 16
    for (int i = 0; i < 16; ++i) {
      const int ch = kg * 16 + i;
      short8 bh = *(const short8*)(s_whi + (size_t)(ch * 64 + lane) * 8);
      short8 bl = *(const short8*)(s_wlo + (size_t)(ch * 64 + lane) * 8);
      acc = __builtin_amdgcn_mfma_f32_16x16x32_bf16(ahv[i], bh, acc, 0, 0, 0);
      acc = __builtin_amdgcn_mfma_f32_16x16x32_bf16(ahv[i], bl, acc, 0, 0, 0);
      acc = __builtin_amdgcn_mfma_f32_16x16x32_bf16(alv[i], bh, acc, 0, 0, 0);
    }

    // ---- K-split reduce through LDS ----
    *(f32x4*)(s_part + ((size_t)w * 64 + lane) * 4) = acc;
    __syncthreads();

    // ---- epilogue: 1 element/thread; write-through x stores ----
    {
      float pre = bias_ep;
#pragma unroll
      for (int g2 = 0; g2 < 4; ++g2)
        pre += s_part[(mw_ep + g2) * 256 + l_ep * 4 + j_ep];
      float xn = 0.5f * xo + 0.5f * tanhf(pre);
      if (t >= len_ep) xn = 0.0f;
      xo = xn;
      out[((size_t)b_ep * T_STEPS + t) * R_DIM + n0 + c_ep] = xn;  // plain store
      uint16_t* xhn = xh + (size_t)nxt * B_DIM * R_DIM;
      uint16_t* xln = xl + (size_t)nxt * B_DIM * R_DIM;
      const uint16_t hh = f2bf(xn);
      st16_agent(xhn + (size_t)b_ep * R_DIM + n0 + c_ep, hh);
      st16_agent(xln + (size_t)b_ep * R_DIM + n0 + c_ep, f2bf(xn - bf2f(hh)));
    }

    if (t == T_STEPS - 1) break;       // no barrier needed after last step

    // ---- half-grid flag barrier (RMW-free; fence hoisted off critical path) ----
    asm volatile("s_waitcnt vmcnt(0)" ::: "memory");  // x stores acked at L3
    __syncthreads();                                  // whole block done
    // prefetch next step's u (read-only; latency hides under the poll)
    {
      const uint16_t* u_row = ubf + ((size_t)(t + 1) * B_DIM + mt + fr) * D_DIM + kg * 192 + koffe;
#pragma unroll
      for (int i = 0; i < 6; ++i) au[i] = *(const short8*)(u_row + i * 32);
    }
    if (w == 0) {
      // invalidate L1+L2 NOW (while waiting): nobody reads x[nxt] lines during
      // step t, so nothing stale can re-enter before the next step.
      __builtin_amdgcn_fence(__ATOMIC_ACQUIRE, "agent");
      st32_agent(flags + (size_t)bid * 16, (uint32_t)(t + 1));
      const uint32_t tgt = (uint32_t)(t + 1);
      const uint32_t* f0 = flags + (size_t)(h * 128 + 0 * 64 + lane) * 16;
      const uint32_t* f1 = flags + (size_t)(h * 128 + 1 * 64 + lane) * 16;
      for (;;) {
        bool ok = (ld32_agent(f0) >= tgt) & (ld32_agent(f1) >= tgt);
        if (__all(ok)) break;
        __builtin_amdgcn_s_sleep(1);
      }
    }
    __syncthreads();
  }
}

extern "C" void kernel_launch(void* const* d_in, const int* in_sizes, int n_in,
                              void* d_out, int out_size, void* d_ws, size_t ws_size,
                              hipStream_t stream) {
  const float* embedded    = (const float*)d_in[0];
  const int*   lengths     = (const int*)d_in[1];
  const float* input_w     = (const float*)d_in[2];
  const float* reservoir_w = (const float*)d_in[3];
  const float* bias        = (const float*)d_in[4];
  const float* init        = (const float*)d_in[5];
  float* out = (float*)d_out;

  // workspace carve (~45 MB)
  char* p = (char*)d_ws;
  uint16_t* Whi = (uint16_t*)p; p += (size_t)R_DIM * R_DIM * 2;
  uint16_t* Wlo = (uint16_t*)p; p += (size_t)R_DIM * R_DIM * 2;
  uint16_t* Iwb = (uint16_t*)p; p += (size_t)R_DIM * D_DIM * 2;
  uint16_t* ubf = (uint16_t*)p; p += (size_t)T_STEPS * B_DIM * D_DIM * 2;
  uint16_t* xh  = (uint16_t*)p; p += (size_t)2 * B_DIM * R_DIM * 2;
  uint16_t* xl  = (uint16_t*)p; p += (size_t)2 * B_DIM * R_DIM * 2;
  uint32_t* flags = (uint32_t*)p; p += (size_t)NBLK * 16 * 4;

  k_split_w<<<1024, 256, 0, stream>>>(reservoir_w, Whi, Wlo, R_DIM * R_DIM);
  k_tobf<<<512, 256, 0, stream>>>(input_w, Iwb, R_DIM * D_DIM);
  k_tobf<<<2048, 256, 0, stream>>>(embedded, ubf, T_STEPS * B_DIM * D_DIM);
  k_init_x<<<(B_DIM * R_DIM) / 256, 256, 0, stream>>>(init, xh, xl, flags);

  (void)hipFuncSetAttribute((const void*)k_persist,
                            hipFuncAttributeMaxDynamicSharedMemorySize, S_TOTAL);

  void* args[] = {(void*)&Whi, (void*)&Wlo, (void*)&Iwb, (void*)&ubf,
                  (void*)&init, (void*)&xh, (void*)&xl, (void*)&bias,
                  (void*)&lengths, (void*)&out, (void*)&flags};
  (void)hipLaunchCooperativeKernel((const void*)k_persist, dim3(NBLK), dim3(NTHR),
                                   args, S_TOTAL, stream);
}